// Round 13
// baseline (100.869 us; speedup 1.0000x reference)
//
#include <hip/hip_runtime.h>
#include <hip/hip_bf16.h>

// Problem constants: N=8192 S=4 Z=64 H=128 K=4 DEG=16. Float tensors are f32.
typedef unsigned short u16;
typedef unsigned int u32;
typedef unsigned long long u64;
using ushort8 = __attribute__((ext_vector_type(8))) unsigned short;
using short8  = __attribute__((ext_vector_type(8))) short;
using f32x4   = __attribute__((ext_vector_type(4))) float;

__device__ __forceinline__ float bf2f(u16 v) {
  union { u32 u; float f; } x; x.u = ((u32)v) << 16; return x.f;
}
__device__ __forceinline__ float u2f(u32 u) {
  union { u32 u; float f; } x; x.u = u; return x.f;
}
__device__ __forceinline__ u16 f2bf(float f) {
  union { u32 u; float f; } x; x.f = f;
  u32 r = x.u + 0x7FFFu + ((x.u >> 16) & 1u);  // RNE
  return (u16)(r >> 16);
}
__device__ __forceinline__ u32 pack2bf(float lo, float hi) {
  return (u32)f2bf(lo) | ((u32)f2bf(hi) << 16);
}
// Split 8 f32 into bf16 hi (truncated) + bf16 lo (rounded residual).
__device__ __forceinline__ void split8(const float* ap, short8& hi, short8& lo) {
  float4 a0 = *(const float4*)ap, a1 = *(const float4*)(ap + 4);
  float e[8] = {a0.x, a0.y, a0.z, a0.w, a1.x, a1.y, a1.z, a1.w};
  u16 h[8], l[8];
  #pragma unroll
  for (int j = 0; j < 8; ++j) {
    u32 b = __float_as_uint(e[j]);
    h[j] = (u16)(b >> 16);
    l[j] = f2bf(e[j] - u2f(b & 0xffff0000u));
  }
  hi = *(short8*)h; lo = *(short8*)l;
}
// Stage a 128x64 f32 chunk into LDS bf16 [128][72], 256-thread version.
__device__ __forceinline__ void stage_w(const float* g, int stride, int c, u16* Wl, int t) {
  int row = t >> 1, half = t & 1;
  const float4* gp = (const float4*)(g + (size_t)row * stride + c * 64 + half * 32);
  ushort8* d = (ushort8*)(Wl + row * 72 + half * 32);
  #pragma unroll
  for (int i = 0; i < 4; ++i) {
    float4 a = gp[2 * i], b = gp[2 * i + 1];
    ushort8 o;
    o[0] = f2bf(a.x); o[1] = f2bf(a.y); o[2] = f2bf(a.z); o[3] = f2bf(a.w);
    o[4] = f2bf(b.x); o[5] = f2bf(b.y); o[6] = f2bf(b.z); o[7] = f2bf(b.w);
    d[i] = o;
  }
}
// Same, 512-thread version.
__device__ __forceinline__ void stage_w512(const float* g, int stride, int c, u16* Wl, int t) {
  int row = t >> 2, q = t & 3;
  const float4* gp = (const float4*)(g + (size_t)row * stride + c * 64 + q * 16);
  ushort8* d = (ushort8*)(Wl + row * 72 + q * 16);
  #pragma unroll
  for (int i = 0; i < 2; ++i) {
    float4 a = gp[2 * i], b = gp[2 * i + 1];
    ushort8 o;
    o[0] = f2bf(a.x); o[1] = f2bf(a.y); o[2] = f2bf(a.z); o[3] = f2bf(a.w);
    o[4] = f2bf(b.x); o[5] = f2bf(b.y); o[6] = f2bf(b.z); o[7] = f2bf(b.w);
    d[i] = o;
  }
}

// K_prep: blocks 0..63: B for td-GEMM pre-split (Bh/Bl[(k*64+z1)*64+z2]);
//         blocks 64..319: WW2 composite; blocks 320..447: zIG -> zh/zl split planes.
__global__ __launch_bounds__(256) void k_prep(const float* __restrict__ Ws,
                                              const float* __restrict__ Wd,
                                              const float* __restrict__ F1w1,
                                              const float* __restrict__ F2w2,
                                              const float* __restrict__ zIG,
                                              u16* __restrict__ Bh, u16* __restrict__ Bl,
                                              float* __restrict__ WW2,
                                              u16* __restrict__ zh, u16* __restrict__ zl) {
  if (blockIdx.x < 64) {
    int t = blockIdx.x * 256 + threadIdx.x;     // 16384 = k(4) x z1(64) x z2(64)
    int k = t >> 12, z1 = (t >> 6) & 63, z2 = t & 63;
    const float* wsp = Ws + k * 8192 + z1;
    const float* wdp = Wd + k * 8192 + z2;
    float acc = 0.f;
    #pragma unroll 8
    for (int h = 0; h < 128; ++h) acc += wsp[h * 64] * wdp[h * 64];
    u32 b = __float_as_uint(acc);
    Bh[(k * 64 + z1) * 64 + z2] = (u16)(b >> 16);
    Bl[(k * 64 + z1) * 64 + z2] = f2bf(acc - u2f(b & 0xffff0000u));
  } else if (blockIdx.x < 320) {
    int id = (blockIdx.x - 64) * 256 + threadIdx.x;  // 65536 = 128 ho x 4 kk x 128 hi
    int ho = id >> 9, kk = (id >> 7) & 3, hi = id & 127;
    const float* wa = F1w1 + ho * 512 + kk * 128;
    const float* wb = F2w2 + hi;
    float acc = 0.f;
    #pragma unroll 8
    for (int j = 0; j < 128; ++j) acc += wa[j] * wb[j * 128];
    WW2[ho * 512 + kk * 128 + hi] = acc * 0.0625f;
  } else {
    // z split: 2097152 f32 = 524288 float4; 32768 threads x 16
    int base = (blockIdx.x - 320) * 256 + threadIdx.x;
    #pragma unroll
    for (int i = 0; i < 16; ++i) {
      int idx = base + i * 32768;
      float4 zv = ((const float4*)zIG)[idx];
      float e[4] = {zv.x, zv.y, zv.z, zv.w};
      u16 h[4], l[4];
      #pragma unroll
      for (int j = 0; j < 4; ++j) {
        u32 b = __float_as_uint(e[j]);
        h[j] = (u16)(b >> 16);
        l[j] = f2bf(e[j] - u2f(b & 0xffff0000u));
      }
      *(u64*)&zh[idx * 4] = *(u64*)h;
      *(u64*)&zl[idx * 4] = *(u64*)l;
    }
  }
}

// K_tduv: blocks 0..1023: td GEMM -> split bf16 output (tdh/tdl);
//         blocks 1024..1535: u or v GEMM.
__global__ __launch_bounds__(256) void k_tduv(const float* __restrict__ zIG,
                                              const u16* __restrict__ Bh_g,
                                              const u16* __restrict__ Bl_g,
                                              const float* __restrict__ xt,
                                              const float* __restrict__ W1,
                                              u16* __restrict__ tdh, u16* __restrict__ tdl,
                                              u16* __restrict__ u, u16* __restrict__ v) {
  __shared__ __align__(16) u16 SM[128 * 72];
  int t = threadIdx.x, lane = t & 63, w = t >> 6;
  int l15 = lane & 15, kc = lane >> 4;
  if (blockIdx.x < 1024) {
    u16* Bh = SM;
    u16* Bl = SM + 64 * 72;
    int cq = blockIdx.x & 3;
    size_t rowbase = (size_t)(blockIdx.x >> 2) * 128 + w * 32;
    {
      int row = t >> 2, q = t & 3;
      const ushort8* gh = (const ushort8*)(Bh_g + (cq * 64 + row) * 64 + q * 16);
      const ushort8* gl = (const ushort8*)(Bl_g + (cq * 64 + row) * 64 + q * 16);
      ushort8* dh = (ushort8*)(Bh + row * 72 + q * 16);
      ushort8* dl = (ushort8*)(Bl + row * 72 + q * 16);
      dh[0] = gh[0]; dh[1] = gh[1];
      dl[0] = gl[0]; dl[1] = gl[1];
    }
    __syncthreads();
    f32x4 acc[2][4];
    #pragma unroll
    for (int mt = 0; mt < 2; ++mt)
      #pragma unroll
      for (int nt = 0; nt < 4; ++nt) acc[mt][nt] = (f32x4){0.f, 0.f, 0.f, 0.f};
    #pragma unroll
    for (int ks = 0; ks < 2; ++ks) {
      short8 ah[2], al[2];
      #pragma unroll
      for (int mt = 0; mt < 2; ++mt)
        split8(zIG + (rowbase + mt * 16 + l15) * 64 + ks * 32 + kc * 8, ah[mt], al[mt]);
      #pragma unroll
      for (int nt = 0; nt < 4; ++nt) {
        int bo = (nt * 16 + l15) * 72 + ks * 32 + kc * 8;
        short8 bh = *(const short8*)&Bh[bo];
        short8 bl = *(const short8*)&Bl[bo];
        #pragma unroll
        for (int mt = 0; mt < 2; ++mt) {
          acc[mt][nt] = __builtin_amdgcn_mfma_f32_16x16x32_bf16(ah[mt], bh, acc[mt][nt], 0, 0, 0);
          acc[mt][nt] = __builtin_amdgcn_mfma_f32_16x16x32_bf16(al[mt], bh, acc[mt][nt], 0, 0, 0);
          acc[mt][nt] = __builtin_amdgcn_mfma_f32_16x16x32_bf16(ah[mt], bl, acc[mt][nt], 0, 0, 0);
        }
      }
    }
    #pragma unroll
    for (int mt = 0; mt < 2; ++mt)
      #pragma unroll
      for (int nt = 0; nt < 4; ++nt)
        #pragma unroll
        for (int j = 0; j < 4; ++j) {
          float val = acc[mt][nt][j];
          size_t idx = (rowbase + mt * 16 + kc * 4 + j) * 256 + cq * 64 + nt * 16 + l15;
          u32 b = __float_as_uint(val);
          tdh[idx] = (u16)(b >> 16);
          tdl[idx] = f2bf(val - u2f(b & 0xffff0000u));
        }
  } else {
    u16* Wl = SM;
    int bid2 = blockIdx.x - 1024;
    int sel = bid2 >> 8;                       // 0 = u, 1 = v
    size_t rowbase = (size_t)(bid2 & 255) * 128 + w * 32;
    const float* Wbase = W1 + sel * 128;
    f32x4 acc[2][8];
    #pragma unroll
    for (int mt = 0; mt < 2; ++mt)
      #pragma unroll
      for (int nt = 0; nt < 8; ++nt) acc[mt][nt] = (f32x4){0.f, 0.f, 0.f, 0.f};
    for (int c = 0; c < 2; ++c) {
      __syncthreads();
      stage_w(Wbase, 256, c, Wl, t);
      __syncthreads();
      #pragma unroll
      for (int ks = 0; ks < 2; ++ks) {
        short8 af[2];
        #pragma unroll
        for (int mt = 0; mt < 2; ++mt) {
          const float* ap = xt + (rowbase + mt * 16 + l15) * 128 + c * 64 + ks * 32 + kc * 8;
          float4 a0 = *(const float4*)ap, a1 = *(const float4*)(ap + 4);
          u16 tmp[8] = {f2bf(a0.x), f2bf(a0.y), f2bf(a0.z), f2bf(a0.w),
                        f2bf(a1.x), f2bf(a1.y), f2bf(a1.z), f2bf(a1.w)};
          af[mt] = *(short8*)tmp;
        }
        #pragma unroll
        for (int nt = 0; nt < 8; ++nt) {
          short8 bw = *(const short8*)&Wl[(nt * 16 + l15) * 72 + ks * 32 + kc * 8];
          #pragma unroll
          for (int mt = 0; mt < 2; ++mt)
            acc[mt][nt] = __builtin_amdgcn_mfma_f32_16x16x32_bf16(af[mt], bw, acc[mt][nt], 0, 0, 0);
        }
      }
    }
    u16* dstp = sel ? v : u;
    #pragma unroll
    for (int mt = 0; mt < 2; ++mt)
      #pragma unroll
      for (int nt = 0; nt < 8; ++nt)
        #pragma unroll
        for (int j = 0; j < 4; ++j)
          dstp[(rowbase + mt * 16 + kc * 4 + j) * 128 + nt * 16 + l15] =
              f2bf(acc[mt][nt][j]);
  }
}

// K_score (MFMA edition): 4 waves/block, wave w owns node n = bid*4+w.
//  Phase B on matrix pipe: C[d][sk] = z_src[d][64] . td[sk][64], split-bf16 x3 terms,
//  frags loaded straight from global (pre-split planes). Softmax in-register
//  (max3 + 2 shfl_xor). One barrier (alpha LDS exchange). Phase D on VALU.
__global__ __launch_bounds__(256) void k_score(
    const u16* __restrict__ zh, const u16* __restrict__ zl,
    const u16* __restrict__ tdh, const u16* __restrict__ tdl,
    const int* __restrict__ src, const u16* __restrict__ uW, const u16* __restrict__ vW,
    float* __restrict__ out, u16* __restrict__ m_ws) {
  __shared__ float a20[4][320];   // [wave][d*20 + sk]

  int t = threadIdx.x, lane = t & 63, w = t >> 6;
  int n = blockIdx.x * 4 + w;
  int l15 = lane & 15, lq = lane >> 4;

  // --- phase B: 24 MFMA. A = z rows (d), B = td rows (sk), K = z-dim 64. ---
  // B frags (same for all s): td[n][sk=l15][kc*32 + lq*8 ..+8], hi & lo.
  const u16* tdh_n = tdh + (size_t)n * 1024;
  const u16* tdl_n = tdl + (size_t)n * 1024;
  short8 bh0 = *(const short8*)(tdh_n + l15 * 64 + lq * 8);
  short8 bh1 = *(const short8*)(tdh_n + l15 * 64 + 32 + lq * 8);
  short8 bl0 = *(const short8*)(tdl_n + l15 * 64 + lq * 8);
  short8 bl1 = *(const short8*)(tdl_n + l15 * 64 + 32 + lq * 8);
  // A frag source row: d = l15
  size_t zrow = (size_t)src[n * 16 + l15] * 256;
  f32x4 acc[4];
  #pragma unroll
  for (int s = 0; s < 4; ++s) {
    short8 ah0 = *(const short8*)(zh + zrow + s * 64 + lq * 8);
    short8 ah1 = *(const short8*)(zh + zrow + s * 64 + 32 + lq * 8);
    short8 al0 = *(const short8*)(zl + zrow + s * 64 + lq * 8);
    short8 al1 = *(const short8*)(zl + zrow + s * 64 + 32 + lq * 8);
    f32x4 a = (f32x4){0.f, 0.f, 0.f, 0.f};
    a = __builtin_amdgcn_mfma_f32_16x16x32_bf16(ah0, bh0, a, 0, 0, 0);
    a = __builtin_amdgcn_mfma_f32_16x16x32_bf16(ah1, bh1, a, 0, 0, 0);
    a = __builtin_amdgcn_mfma_f32_16x16x32_bf16(al0, bh0, a, 0, 0, 0);
    a = __builtin_amdgcn_mfma_f32_16x16x32_bf16(al1, bh1, a, 0, 0, 0);
    a = __builtin_amdgcn_mfma_f32_16x16x32_bf16(ah0, bl0, a, 0, 0, 0);
    a = __builtin_amdgcn_mfma_f32_16x16x32_bf16(ah1, bl1, a, 0, 0, 0);
    acc[s] = a;
  }
  // select valid s-block: lane's col sk = l15 belongs to s = l15>>2.
  int qsel = l15 >> 2;
  float sc[4];
  #pragma unroll
  for (int j = 0; j < 4; ++j) {
    float a01 = (qsel == 0) ? acc[0][j] : acc[1][j];
    float a23 = (qsel == 2) ? acc[2][j] : acc[3][j];
    float vsc = (qsel < 2) ? a01 : a23;
    sc[j] = vsc > 0.f ? vsc : 0.01f * vsc;   // leaky_relu
  }
  // --- phase C: softmax over d = rows (lq, j): max3 over j + shfl_xor 16,32 ---
  float mx = fmaxf(fmaxf(sc[0], sc[1]), fmaxf(sc[2], sc[3]));
  mx = fmaxf(mx, __shfl_xor(mx, 16));
  mx = fmaxf(mx, __shfl_xor(mx, 32));
  float e0 = __expf(sc[0] - mx), e1 = __expf(sc[1] - mx);
  float e2 = __expf(sc[2] - mx), e3 = __expf(sc[3] - mx);
  float esum = (e0 + e1) + (e2 + e3);
  esum += __shfl_xor(esum, 16);
  esum += __shfl_xor(esum, 32);
  float inv = 1.0f / esum;
  float al[4] = {e0 * inv, e1 * inv, e2 * inv, e3 * inv};
  {  // alpha -> global (exact f32) + LDS for phase D
    float* ob = out + 4194304u + (unsigned)n * 256;
    #pragma unroll
    for (int j = 0; j < 4; ++j) {
      int d = lq * 4 + j;
      ob[d * 16 + l15] = al[j];
      a20[w][d * 20 + l15] = al[j];
    }
  }
  __syncthreads();
  // --- phase D: mailbox m[sk][h] = sum_d alpha * relu(u[src]+v[n]) ---
  int sidx[16];
  #pragma unroll
  for (int dd = 0; dd < 16; ++dd) sidx[dd] = src[n * 16 + dd];
  const u32* up = (const u32*)uW;
  u32* mp = (u32*)(m_ws + (size_t)n * 2048);
  #pragma unroll
  for (int s = 0; s < 4; ++s) {
    u32 vb = *(const u32*)(vW + (size_t)n * 512 + s * 128 + lane * 2);
    float v_lo = u2f(vb << 16), v_hi = u2f(vb & 0xffff0000u);
    u32 ub[16];
    #pragma unroll
    for (int dd = 0; dd < 16; ++dd)
      ub[dd] = up[(size_t)sidx[dd] * 256 + s * 64 + lane];
    float m0l = 0.f, m0h = 0.f, m1l = 0.f, m1h = 0.f;
    float m2l = 0.f, m2h = 0.f, m3l = 0.f, m3h = 0.f;
    #pragma unroll
    for (int dd = 0; dd < 16; ++dd) {
      float r_lo = fmaxf(u2f(ub[dd] << 16) + v_lo, 0.f);
      float r_hi = fmaxf(u2f(ub[dd] & 0xffff0000u) + v_hi, 0.f);
      float4 a = *(const float4*)&a20[w][dd * 20 + s * 4];
      m0l += a.x * r_lo; m0h += a.x * r_hi;
      m1l += a.y * r_lo; m1h += a.y * r_hi;
      m2l += a.z * r_lo; m2h += a.z * r_hi;
      m3l += a.w * r_lo; m3h += a.w * r_hi;
    }
    mp[(s * 4 + 0) * 64 + lane] = pack2bf(m0l, m0h);
    mp[(s * 4 + 1) * 64 + lane] = pack2bf(m1l, m1h);
    mp[(s * 4 + 2) * 64 + lane] = pack2bf(m2l, m2h);
    mp[(s * 4 + 3) * 64 + lane] = pack2bf(m3l, m3h);
  }
}

// K4: fused F+G, 512 threads / 8 waves (16 rows per wave).
__global__ __launch_bounds__(512) void k_fg(const u16* __restrict__ A,
                                            const float* __restrict__ WF,
                                            const float* __restrict__ WG,
                                            float* __restrict__ out) {
  __shared__ u16 Wl[128 * 72];
  __shared__ u16 hidl[128 * 136];
  int t = threadIdx.x, lane = t & 63, w = t >> 6;
  size_t rowbase = (size_t)blockIdx.x * 128 + w * 16;
  int l15 = lane & 15, kc = lane >> 4;
  f32x4 acc[8];
  #pragma unroll
  for (int nt = 0; nt < 8; ++nt) acc[nt] = (f32x4){0.f, 0.f, 0.f, 0.f};
  for (int c = 0; c < 8; ++c) {
    __syncthreads();
    stage_w512(WF, 512, c, Wl, t);
    __syncthreads();
    #pragma unroll
    for (int ks = 0; ks < 2; ++ks) {
      short8 af = *(const short8*)(A + (rowbase + l15) * 512 + c * 64 + ks * 32 + kc * 8);
      #pragma unroll
      for (int nt = 0; nt < 8; ++nt) {
        short8 bf = *(const short8*)&Wl[(nt * 16 + l15) * 72 + ks * 32 + kc * 8];
        acc[nt] = __builtin_amdgcn_mfma_f32_16x16x32_bf16(af, bf, acc[nt], 0, 0, 0);
      }
    }
  }
  #pragma unroll
  for (int nt = 0; nt < 8; ++nt)
    #pragma unroll
    for (int j = 0; j < 4; ++j)
      hidl[(w * 16 + kc * 4 + j) * 136 + nt * 16 + l15] = f2bf(fmaxf(acc[nt][j], 0.f));
  f32x4 acc2[8];
  #pragma unroll
  for (int nt = 0; nt < 8; ++nt) acc2[nt] = (f32x4){0.f, 0.f, 0.f, 0.f};
  for (int c = 0; c < 2; ++c) {
    __syncthreads();
    stage_w512(WG, 128, c, Wl, t);
    __syncthreads();
    #pragma unroll
    for (int ks = 0; ks < 2; ++ks) {
      short8 af = *(const short8*)&hidl[(w * 16 + l15) * 136 + c * 64 + ks * 32 + kc * 8];
      #pragma unroll
      for (int nt = 0; nt < 8; ++nt) {
        short8 bf = *(const short8*)&Wl[(nt * 16 + l15) * 72 + ks * 32 + kc * 8];
        acc2[nt] = __builtin_amdgcn_mfma_f32_16x16x32_bf16(af, bf, acc2[nt], 0, 0, 0);
      }
    }
  }
  #pragma unroll
  for (int nt = 0; nt < 8; ++nt)
    #pragma unroll
    for (int j = 0; j < 4; ++j)
      out[(rowbase + kc * 4 + j) * 128 + nt * 16 + l15] = acc2[nt][j];
}

extern "C" void kernel_launch(void* const* d_in, const int* in_sizes, int n_in,
                              void* d_out, int out_size, void* d_ws, size_t ws_size,
                              hipStream_t stream) {
  const float* zIG  = (const float*)d_in[0];
  const float* xt   = (const float*)d_in[1];
  const float* Ws   = (const float*)d_in[2];
  const float* Wd   = (const float*)d_in[3];
  const float* F2w1 = (const float*)d_in[4];
  const float* F2w2 = (const float*)d_in[5];
  const float* F1w1 = (const float*)d_in[6];
  const float* F1w2 = (const float*)d_in[7];
  const int* src    = (const int*)d_in[8];
  float* out = (float*)d_out;

  char* ws = (char*)d_ws;
  u16* Bh    = (u16*)ws;                             // 32 KiB
  u16* Bl    = (u16*)(ws + 32768);                   // 32 KiB
  u16* tdh   = (u16*)(ws + 65536);                   // 16 MiB
  u16* tdl   = (u16*)(ws + 16842752);                // 16 MiB
  u16* u     = (u16*)(ws + 33619968);                // 8 MiB
  u16* v     = (u16*)(ws + 42008576);                // 8 MiB
  u16* zh    = (u16*)(ws + 50397184);                // 4 MiB
  u16* zl    = (u16*)(ws + 54591488);                // 4 MiB
  float* WW2 = (float*)(ws + 58785792);              // 256 KiB
  u16* m     = (u16*)(ws + 59047936);                // 32 MiB  (end ~88.3 MiB)

  k_prep <<<448,  256, 0, stream>>>(Ws, Wd, F1w1, F2w2, zIG, Bh, Bl, WW2, zh, zl);
  k_tduv <<<1536, 256, 0, stream>>>(zIG, Bh, Bl, xt, F2w1, tdh, tdl, u, v);
  k_score<<<2048, 256, 0, stream>>>(zh, zl, tdh, tdl, src, u, v, out, m);
  k_fg   <<<256,  512, 0, stream>>>(m, WW2, F1w2, out);
}